// Round 9
// baseline (1296.476 us; speedup 1.0000x reference)
//
#include <hip/hip_runtime.h>
#include <hip/hip_bf16.h>

// HunyuanTopKGate: x[4096,4096] fp32, wg[64,4096] fp32 ->
//   combine_weights [T,E,C] fp32 ++ dispatch_mask [T,E,C] (as fp32 0/1)
// C = out_size/(2*T*E) = 2268 -> 4.76 GB output zero-fill (~760us at the
// 6.2 TB/s fill ceiling) is the roofline pole (one stream: nothing overlaps).
//
// Round 9: UN-FUSE. R7-R8=25us proved verify+repair were clean/cheap in R7,
// => the fused gemm+fill kernel itself was ~1250us: fusion never overlapped
// (the 1-block/CU gemm is a latency-bound straggler under fill interference).
// Plan: memset via hipMemsetAsync (proven 6.2TB/s) + the PROVEN 16-tok gemm
// at split-K x8 (2048 blocks -> 8 waves/SIMD, latency hidden -> ~80-110us;
// only k-bounds/slab-output differ from the proven kernel). verify+repair
// kept (+25us clean) to guard the refactor; rank+scatter fused (one less
// dispatch). Expected ~880-915us.
//
// ws: partial[8][4096][64] f64 (16MB) | idx_kt(128KB) | w_kt(128KB) | flag

#define TOK 4096
#define HID 4096
#define NE  64
#define NK  8

// ---------------- 1. split-K fp64 GEMM (R1-proven inner structure) -------
// Grid (256 token-tiles, nsplit slabs), 256 thr. Per block: 16 tokens x
// 64 experts x kchunk. thread = (tok=tid&15) x (4 experts at (tid>>4)*4).
__global__ __launch_bounds__(256) void gemm_splitk(
    const float* __restrict__ x, const float* __restrict__ wg,
    double* __restrict__ partial, int kchunk, int* __restrict__ flag) {
  __shared__ float xs[16][68];
  __shared__ float wsh[64][68];
  const int tid = threadIdx.x;
  if (blockIdx.x == 0 && blockIdx.y == 0 && tid == 0) *flag = 0;
  const int t0  = blockIdx.x * 16;
  const int k0  = blockIdx.y * kchunk;
  const int tok = tid & 15;
  const int eg  = tid >> 4;          // experts eg*4..eg*4+3
  const int lrow = tid >> 4;
  const int lq   = tid & 15;
  double acc[4] = {0.0, 0.0, 0.0, 0.0};

  for (int s = 0; s < kchunk; s += 64) {
    const int kk = k0 + s;
    {
      float4 v = *(const float4*)&x[(size_t)(t0 + lrow) * HID + kk + lq * 4];
      *(float4*)&xs[lrow][lq * 4] = v;
    }
#pragma unroll
    for (int it = 0; it < 4; ++it) {
      int r = it * 16 + lrow;
      float4 v = *(const float4*)&wg[(size_t)r * HID + kk + lq * 4];
      *(float4*)&wsh[r][lq * 4] = v;
    }
    __syncthreads();
#pragma unroll
    for (int kc = 0; kc < 64; kc += 4) {
      float4 xv = *(const float4*)&xs[tok][kc];
#pragma unroll
      for (int j = 0; j < 4; ++j) {
        float4 wv = *(const float4*)&wsh[eg * 4 + j][kc];
        acc[j] = fma((double)xv.x, (double)wv.x, acc[j]);
        acc[j] = fma((double)xv.y, (double)wv.y, acc[j]);
        acc[j] = fma((double)xv.z, (double)wv.z, acc[j]);
        acc[j] = fma((double)xv.w, (double)wv.w, acc[j]);
      }
    }
    __syncthreads();
  }
  double* base = partial + (size_t)blockIdx.y * TOK * NE;
#pragma unroll
  for (int j = 0; j < 4; ++j)
    base[(size_t)(t0 + tok) * NE + eg * 4 + j] = acc[j];
}

// ---------------- 1b. verify: sample 512 logits vs exact fp64 dots --------
// Proven: correctly flagged the broken MFMA gemms (R3/R5) and correctly
// passed the vector gemm (R7: +25us total with repair early-exit).
__global__ __launch_bounds__(256) void verify_kernel(
    const float* __restrict__ x, const float* __restrict__ wg,
    const double* __restrict__ partial, int nsplit, int* __restrict__ flag) {
  const int gid  = blockIdx.x * blockDim.x + threadIdx.x;
  const int wid  = gid >> 6;          // 0..511
  const int lane = gid & 63;
  const int t = (wid * 521) & (TOK - 1);
  const int e = wid & 63;
  double acc = 0.0;
  for (int k = lane; k < HID; k += 64)
    acc = fma((double)x[(size_t)t * HID + k], (double)wg[(size_t)e * HID + k], acc);
#pragma unroll
  for (int off = 32; off; off >>= 1) acc += __shfl_xor(acc, off);
  if (lane == 0) {
    double got = 0.0;
    for (int p = 0; p < nsplit; ++p)
      got += partial[(size_t)p * TOK * NE + (size_t)t * NE + e];
    if (!(fabs(got - acc) <= 1e-6)) atomicOr(flag, 1);  // NaN-safe
  }
}

// ---------------- 1c. repair: ILP-8 fp64 recompute if flag set -----------
// Wave = one token row (x broadcast), lane = expert. wg streams from L2
// (~4GB @ 34 TB/s ~ 120us) + VALU ~100us. Contingency only.
__global__ __launch_bounds__(256) void repair_gemm(
    const float* __restrict__ x, const float* __restrict__ wg,
    double* __restrict__ partial, int nsplit, const int* __restrict__ flag) {
  if (*(volatile const int*)flag == 0) return;
  const int gid = blockIdx.x * 256 + threadIdx.x;   // 0..262143
  const int t = gid >> 6;
  const int e = gid & 63;
  double a0 = 0, a1 = 0, a2 = 0, a3 = 0, a4 = 0, a5 = 0, a6 = 0, a7 = 0;
  const float* xr = x  + (size_t)t * HID;
  const float* wr = wg + (size_t)e * HID;
  for (int k = 0; k < HID; k += 8) {
    float4 xv0 = *(const float4*)&xr[k];
    float4 xv1 = *(const float4*)&xr[k + 4];
    float4 wv0 = *(const float4*)&wr[k];
    float4 wv1 = *(const float4*)&wr[k + 4];
    a0 = fma((double)xv0.x, (double)wv0.x, a0);
    a1 = fma((double)xv0.y, (double)wv0.y, a1);
    a2 = fma((double)xv0.z, (double)wv0.z, a2);
    a3 = fma((double)xv0.w, (double)wv0.w, a3);
    a4 = fma((double)xv1.x, (double)wv1.x, a4);
    a5 = fma((double)xv1.y, (double)wv1.y, a5);
    a6 = fma((double)xv1.z, (double)wv1.z, a6);
    a7 = fma((double)xv1.w, (double)wv1.w, a7);
  }
  partial[(size_t)t * NE + e] =
      ((((((a0 + a1) + a2) + a3) + a4) + a5) + a6) + a7;
  for (int p = 1; p < nsplit; ++p)
    partial[(size_t)p * TOK * NE + (size_t)t * NE + e] = 0.0;
}

// ---------------- 2. softmax + top-8 per token (one wave64/token) ----------
// Fixed-order nsplit sum (deterministic); fp64 softmax; selection key =
// fp32-rounded gate, tie -> lower index. Proven R3/R5/R6.
__global__ __launch_bounds__(256) void topk_kernel(
    const double* __restrict__ partial, int nsplit,
    int* __restrict__ idx_kt, float* __restrict__ w_kt) {
  const int gid  = blockIdx.x * blockDim.x + threadIdx.x;
  const int t    = gid >> 6;
  const int lane = gid & 63;

  double v = 0.0;
  for (int p = 0; p < nsplit; ++p)
    v += partial[(size_t)p * TOK * NE + (size_t)t * NE + lane];

  double m = v;
#pragma unroll
  for (int off = 32; off; off >>= 1) {
    double o = __shfl_xor(m, off);
    m = o > m ? o : m;
  }
  double g = exp(v - m);
  double s = g;
#pragma unroll
  for (int off = 32; off; off >>= 1) s += __shfl_xor(s, off);
  double gate = g / s;

  float key = (float)gate;
  double ssel = 0.0;
  int my_k = -1;
#pragma unroll
  for (int k = 0; k < NK; ++k) {
    float bv = key;
    int   bi = lane;
#pragma unroll
    for (int off = 32; off; off >>= 1) {
      float ov = __shfl_xor(bv, off);
      int   oi = __shfl_xor(bi, off);
      if (ov > bv || (ov == bv && oi < bi)) { bv = ov; bi = oi; }
    }
    ssel += __shfl(gate, bi);
    if (lane == bi) { my_k = k; key = -1.0f; }
  }
  double gs = ssel;
  const double eps = (double)1.1920929e-07f;
  if (gs < eps) gs = eps;

  if (my_k >= 0) {
    idx_kt[my_k * TOK + t] = lane;
    w_kt [my_k * TOK + t] = (float)(gate / gs);
  }
}

// ---------------- 3. fused rank + scatter ------------------------------
// One block per expert; stable prefix count over the k-major scan order
// (proven rank logic), and each hit writes its output slot directly.
__global__ __launch_bounds__(1024) void rank_scatter(
    const int* __restrict__ idx_kt, const float* __restrict__ w_kt,
    float* __restrict__ out, int C) {
  const int e    = blockIdx.x;
  const int tid  = threadIdx.x;
  const int lane = tid & 63;
  const int w    = tid >> 6;          // 0..15
  __shared__ int wt[16];
  int running = 0;
  const unsigned long long below = (1ull << lane) - 1ull;

  for (int i0 = 0; i0 < NK * TOK; i0 += 1024) {
    const int i = i0 + tid;
    const bool mhit = (idx_kt[i] == e);
    unsigned long long mask = __ballot(mhit);
    if (lane == 0) wt[w] = __popcll(mask);
    __syncthreads();
    int woff = 0, tot = 0;
#pragma unroll
    for (int j = 0; j < 16; ++j) {
      int c = wt[j];
      tot += c;
      if (j < w) woff += c;
    }
    if (mhit) {
      const int c = running + woff + __popcll(mask & below);
      if (c < C) {
        const int t = i & (TOK - 1);
        size_t off = ((size_t)t * NE + e) * (size_t)C + (size_t)c;
        out[off] = w_kt[i];                          // combine_weights
        out[(size_t)TOK * NE * C + off] = 1.0f;      // dispatch_mask
      }
    }
    running += tot;
    __syncthreads();
  }
}

extern "C" void kernel_launch(void* const* d_in, const int* in_sizes, int n_in,
                              void* d_out, int out_size, void* d_ws, size_t ws_size,
                              hipStream_t stream) {
  const float* x  = (const float*)d_in[0];   // [4096,4096]
  const float* wg = (const float*)d_in[1];   // [64,4096]
  float* out = (float*)d_out;

  const int C = out_size / (2 * TOK * NE);   // capacity from output size

  const size_t slab = (size_t)TOK * NE * sizeof(double);   // 2 MB per partial
  const size_t tail = 2 * (size_t)NK * TOK * sizeof(int);  // idx + w
  int nsplit = 8;
  while (nsplit > 1 && (size_t)nsplit * slab + tail + 64 > ws_size) nsplit >>= 1;
  const int kchunk = HID / nsplit;

  char* ws = (char*)d_ws;
  double* partial = (double*)ws;
  int*    idx_kt  = (int*)  (ws + (size_t)nsplit * slab);
  float*  w_kt    = (float*)(ws + (size_t)nsplit * slab + (size_t)NK * TOK * 4);
  int*    flag    = (int*)  (ws + (size_t)nsplit * slab + tail);

  // zero the 4.76 GB output (poisoned 0xAA before every timed launch) —
  // hipMemsetAsync/fillBufferAligned is the proven-at-ceiling path (~760us).
  hipMemsetAsync(d_out, 0, (size_t)out_size * sizeof(float), stream);

  dim3 ggrid(TOK / 16, nsplit);   // 256 x 8 = 2048 blocks -> 8 waves/SIMD
  gemm_splitk <<<ggrid, 256, 0, stream>>>(x, wg, partial, kchunk, flag);
  verify_kernel<<<128, 256, 0, stream>>>(x, wg, partial, nsplit, flag);
  repair_gemm <<<TOK * NE / 256, 256, 0, stream>>>(x, wg, partial, nsplit, flag);
  topk_kernel <<<TOK * 64 / 256, 256, 0, stream>>>(partial, nsplit, idx_kt, w_kt);
  rank_scatter<<<NE, 1024, 0, stream>>>(idx_kt, w_kt, out, C);
}

// Round 10
// 1237.042 us; speedup vs baseline: 1.0480x; 1.0480x over previous
//
#include <hip/hip_runtime.h>
#include <hip/hip_bf16.h>

// HunyuanTopKGate: x[4096,4096] fp32, wg[64,4096] fp32 ->
//   combine_weights [T,E,C] fp32 ++ dispatch_mask [T,E,C] (as fp32 0/1)
// C = out_size/(2*T*E) = 2268 -> 4.76 GB output zero-fill (~765us at the
// 6.2 TB/s fill ceiling) is the roofline pole.
//
// Round 10: R9 proved the fp64 VECTOR gemm is ~500us regardless of
// occupancy (R1 full-K 1 wave/SIMD = 550; R9 split-K 8 waves/SIMD = ~500)
// -> fp64 VALU throughput on gfx950 is the wall. Switch the arithmetic:
// bf16x3 split GEMM on mfma_f32_16x16x32_bf16 -- the ONE MFMA whose
// layouts are HW-verified (docs m89/m91/m120): A[m=lane&15][k=quad*8+j],
// B^T[n=lane&15][k=quad*8+j] (wg's [E][K] is exactly B^T), C/D
// row=quad*4+reg, col=lane&15. a=a1+a2+a3 (bf16), 6 cross-term MFMAs
// chained into one fp32 acc -> logit error ~1e-6 (same order as the np
// reference's own fp32 noise, which provably flips nothing on this data).
// verify(tol 1e-3) -> gated repair = R9's PROVEN fp64 split-K gemm, so
// worst case = today's ~1296, best ~860.
//
// ws: partial[8][4096][64] f64 (16MB) | idx_kt | w_kt | flag

#define TOK 4096
#define HID 4096
#define NE  64
#define NK  8

typedef __attribute__((ext_vector_type(8))) short short8;   // 8 bf16
typedef __attribute__((ext_vector_type(4))) float f32x4;

__device__ __forceinline__ short f2bf(float f) {
  __hip_bfloat16 h = __float2bfloat16(f);   // RNE
  return *reinterpret_cast<short*>(&h);
}
__device__ __forceinline__ float bf2f(short s) {
  unsigned u = ((unsigned)(unsigned short)s) << 16;
  return __uint_as_float(u);
}
__device__ __forceinline__ void cvt3(float f, short& s0, short& s1, short& s2) {
  s0 = f2bf(f);
  float r1 = f - bf2f(s0);
  s1 = f2bf(r1);
  float r2 = r1 - bf2f(s1);
  s2 = f2bf(r2);
}

// ---------------- 1. bf16x3 MFMA GEMM ----------------
// Grid (64 token-tiles, nsplit k-slabs), 256 thr = 4 waves.
// Block: 64 tokens x 64 experts x kchunk. Wave w: token rows w*16..+15,
// all 4 expert 16-col tiles. LDS: 3 bf16 planes for x and wg, row stride
// 72 shorts (144B = 9*16: b128 frag reads 16B-aligned, 2-way banks = free).
__global__ __launch_bounds__(256) void gemm_bf16x3(
    const float* __restrict__ x, const float* __restrict__ wg,
    double* __restrict__ partial, int kchunk, int* __restrict__ flag) {
  __shared__ __align__(16) short XA[3][64][72];   // 27.6 KB
  __shared__ __align__(16) short WB[3][64][72];   // 27.6 KB
  const int tid = threadIdx.x;
  if (blockIdx.x == 0 && blockIdx.y == 0 && tid == 0) *flag = 0;
  const int t0   = blockIdx.x * 64;
  const int k0   = blockIdx.y * kchunk;
  const int lane = tid & 63;
  const int w    = tid >> 6;
  const int m    = lane & 15;       // frag row/col within 16
  const int q    = lane >> 4;       // quad
  const int lrow = tid >> 2;        // staging: 4 threads per row
  const int lq   = tid & 3;         // 16 floats each

  f32x4 acc[4];
#pragma unroll
  for (int nt = 0; nt < 4; ++nt) acc[nt] = (f32x4){0.f, 0.f, 0.f, 0.f};

  for (int s = 0; s < kchunk; s += 64) {
    const int kk = k0 + s;
#pragma unroll
    for (int c = 0; c < 4; ++c) {
      const int col = lq * 16 + c * 4;
      float4 xv = *(const float4*)&x [(size_t)(t0 + lrow) * HID + kk + col];
      float4 wv = *(const float4*)&wg[(size_t)lrow * HID + kk + col];
      short4 p0, p1, p2;
      cvt3(xv.x, p0.x, p1.x, p2.x);  cvt3(xv.y, p0.y, p1.y, p2.y);
      cvt3(xv.z, p0.z, p1.z, p2.z);  cvt3(xv.w, p0.w, p1.w, p2.w);
      *(short4*)&XA[0][lrow][col] = p0;
      *(short4*)&XA[1][lrow][col] = p1;
      *(short4*)&XA[2][lrow][col] = p2;
      cvt3(wv.x, p0.x, p1.x, p2.x);  cvt3(wv.y, p0.y, p1.y, p2.y);
      cvt3(wv.z, p0.z, p1.z, p2.z);  cvt3(wv.w, p0.w, p1.w, p2.w);
      *(short4*)&WB[0][lrow][col] = p0;
      *(short4*)&WB[1][lrow][col] = p1;
      *(short4*)&WB[2][lrow][col] = p2;
    }
    __syncthreads();
#pragma unroll
    for (int kc = 0; kc < 64; kc += 32) {
      short8 a0 = *(const short8*)&XA[0][w * 16 + m][kc + q * 8];
      short8 a1 = *(const short8*)&XA[1][w * 16 + m][kc + q * 8];
      short8 a2 = *(const short8*)&XA[2][w * 16 + m][kc + q * 8];
#pragma unroll
      for (int nt = 0; nt < 4; ++nt) {
        short8 b0 = *(const short8*)&WB[0][nt * 16 + m][kc + q * 8];
        short8 b1 = *(const short8*)&WB[1][nt * 16 + m][kc + q * 8];
        short8 b2 = *(const short8*)&WB[2][nt * 16 + m][kc + q * 8];
        acc[nt] = __builtin_amdgcn_mfma_f32_16x16x32_bf16(a0, b0, acc[nt], 0, 0, 0);
        acc[nt] = __builtin_amdgcn_mfma_f32_16x16x32_bf16(a0, b1, acc[nt], 0, 0, 0);
        acc[nt] = __builtin_amdgcn_mfma_f32_16x16x32_bf16(a1, b0, acc[nt], 0, 0, 0);
        acc[nt] = __builtin_amdgcn_mfma_f32_16x16x32_bf16(a0, b2, acc[nt], 0, 0, 0);
        acc[nt] = __builtin_amdgcn_mfma_f32_16x16x32_bf16(a1, b1, acc[nt], 0, 0, 0);
        acc[nt] = __builtin_amdgcn_mfma_f32_16x16x32_bf16(a2, b0, acc[nt], 0, 0, 0);
      }
    }
    __syncthreads();
  }

  // C/D: row = q*4 + v (token), col = m (expert within n-tile)  [m89/m91]
  double* base = partial + (size_t)blockIdx.y * TOK * NE;
#pragma unroll
  for (int nt = 0; nt < 4; ++nt)
#pragma unroll
    for (int v = 0; v < 4; ++v)
      base[(size_t)(t0 + w * 16 + q * 4 + v) * NE + nt * 16 + m] =
          (double)acc[nt][v];
}

// ---------------- 1b. verify: sample 512 logits vs exact fp64 dots --------
// tol 1e-3: passes bf16x3 noise (~1e-5 max), catches layout bugs (O(0.1+)).
__global__ __launch_bounds__(256) void verify_kernel(
    const float* __restrict__ x, const float* __restrict__ wg,
    const double* __restrict__ partial, int nsplit, int* __restrict__ flag) {
  const int gid  = blockIdx.x * blockDim.x + threadIdx.x;
  const int wid  = gid >> 6;          // 0..511
  const int lane = gid & 63;
  const int t = (wid * 521) & (TOK - 1);
  const int e = wid & 63;
  double acc = 0.0;
  for (int k = lane; k < HID; k += 64)
    acc = fma((double)x[(size_t)t * HID + k], (double)wg[(size_t)e * HID + k], acc);
#pragma unroll
  for (int off = 32; off; off >>= 1) acc += __shfl_xor(acc, off);
  if (lane == 0) {
    double got = 0.0;
    for (int p = 0; p < nsplit; ++p)
      got += partial[(size_t)p * TOK * NE + (size_t)t * NE + e];
    if (!(fabs(got - acc) <= 1e-3)) atomicOr(flag, 1);  // NaN-safe
  }
}

// ---------------- 1c. repair: R9's proven fp64 split-K gemm, flag-gated ---
__global__ __launch_bounds__(256) void repair_splitk(
    const float* __restrict__ x, const float* __restrict__ wg,
    double* __restrict__ partial, int kchunk, const int* __restrict__ flag) {
  if (*(volatile const int*)flag == 0) return;
  __shared__ float xs[16][68];
  __shared__ float wsh[64][68];
  const int tid = threadIdx.x;
  const int t0  = blockIdx.x * 16;
  const int k0  = blockIdx.y * kchunk;
  const int tok = tid & 15;
  const int eg  = tid >> 4;
  const int lrow = tid >> 4;
  const int lq   = tid & 15;
  double acc[4] = {0.0, 0.0, 0.0, 0.0};

  for (int s = 0; s < kchunk; s += 64) {
    const int kk = k0 + s;
    {
      float4 v = *(const float4*)&x[(size_t)(t0 + lrow) * HID + kk + lq * 4];
      *(float4*)&xs[lrow][lq * 4] = v;
    }
#pragma unroll
    for (int it = 0; it < 4; ++it) {
      int r = it * 16 + lrow;
      float4 v = *(const float4*)&wg[(size_t)r * HID + kk + lq * 4];
      *(float4*)&wsh[r][lq * 4] = v;
    }
    __syncthreads();
#pragma unroll
    for (int kc = 0; kc < 64; kc += 4) {
      float4 xv = *(const float4*)&xs[tok][kc];
#pragma unroll
      for (int j = 0; j < 4; ++j) {
        float4 wv = *(const float4*)&wsh[eg * 4 + j][kc];
        acc[j] = fma((double)xv.x, (double)wv.x, acc[j]);
        acc[j] = fma((double)xv.y, (double)wv.y, acc[j]);
        acc[j] = fma((double)xv.z, (double)wv.z, acc[j]);
        acc[j] = fma((double)xv.w, (double)wv.w, acc[j]);
      }
    }
    __syncthreads();
  }
  double* base = partial + (size_t)blockIdx.y * TOK * NE;
#pragma unroll
  for (int j = 0; j < 4; ++j)
    base[(size_t)(t0 + tok) * NE + eg * 4 + j] = acc[j];
}

// ---------------- 2. softmax + top-8 per token (one wave64/token) ----------
__global__ __launch_bounds__(256) void topk_kernel(
    const double* __restrict__ partial, int nsplit,
    int* __restrict__ idx_kt, float* __restrict__ w_kt) {
  const int gid  = blockIdx.x * blockDim.x + threadIdx.x;
  const int t    = gid >> 6;
  const int lane = gid & 63;

  double v = 0.0;
  for (int p = 0; p < nsplit; ++p)
    v += partial[(size_t)p * TOK * NE + (size_t)t * NE + lane];

  double m = v;
#pragma unroll
  for (int off = 32; off; off >>= 1) {
    double o = __shfl_xor(m, off);
    m = o > m ? o : m;
  }
  double g = exp(v - m);
  double s = g;
#pragma unroll
  for (int off = 32; off; off >>= 1) s += __shfl_xor(s, off);
  double gate = g / s;

  float key = (float)gate;    // fp32-rounded key, tie -> lower index
  double ssel = 0.0;
  int my_k = -1;
#pragma unroll
  for (int k = 0; k < NK; ++k) {
    float bv = key;
    int   bi = lane;
#pragma unroll
    for (int off = 32; off; off >>= 1) {
      float ov = __shfl_xor(bv, off);
      int   oi = __shfl_xor(bi, off);
      if (ov > bv || (ov == bv && oi < bi)) { bv = ov; bi = oi; }
    }
    ssel += __shfl(gate, bi);
    if (lane == bi) { my_k = k; key = -1.0f; }
  }
  double gs = ssel;
  const double eps = (double)1.1920929e-07f;
  if (gs < eps) gs = eps;

  if (my_k >= 0) {
    idx_kt[my_k * TOK + t] = lane;
    w_kt [my_k * TOK + t] = (float)(gate / gs);
  }
}

// ---------------- 3. fused rank + scatter ------------------------------
__global__ __launch_bounds__(1024) void rank_scatter(
    const int* __restrict__ idx_kt, const float* __restrict__ w_kt,
    float* __restrict__ out, int C) {
  const int e    = blockIdx.x;
  const int tid  = threadIdx.x;
  const int lane = tid & 63;
  const int w    = tid >> 6;          // 0..15
  __shared__ int wt[16];
  int running = 0;
  const unsigned long long below = (1ull << lane) - 1ull;

  for (int i0 = 0; i0 < NK * TOK; i0 += 1024) {
    const int i = i0 + tid;
    const bool mhit = (idx_kt[i] == e);
    unsigned long long mask = __ballot(mhit);
    if (lane == 0) wt[w] = __popcll(mask);
    __syncthreads();
    int woff = 0, tot = 0;
#pragma unroll
    for (int j = 0; j < 16; ++j) {
      int c = wt[j];
      tot += c;
      if (j < w) woff += c;
    }
    if (mhit) {
      const int c = running + woff + __popcll(mask & below);
      if (c < C) {
        const int t = i & (TOK - 1);
        size_t off = ((size_t)t * NE + e) * (size_t)C + (size_t)c;
        out[off] = w_kt[i];                          // combine_weights
        out[(size_t)TOK * NE * C + off] = 1.0f;      // dispatch_mask
      }
    }
    running += tot;
    __syncthreads();
  }
}

extern "C" void kernel_launch(void* const* d_in, const int* in_sizes, int n_in,
                              void* d_out, int out_size, void* d_ws, size_t ws_size,
                              hipStream_t stream) {
  const float* x  = (const float*)d_in[0];   // [4096,4096]
  const float* wg = (const float*)d_in[1];   // [64,4096]
  float* out = (float*)d_out;

  const int C = out_size / (2 * TOK * NE);   // capacity from output size

  const size_t slab = (size_t)TOK * NE * sizeof(double);   // 2 MB per partial
  const size_t tail = 2 * (size_t)NK * TOK * sizeof(int);  // idx + w
  int nsplit = 8;
  while (nsplit > 1 && (size_t)nsplit * slab + tail + 64 > ws_size) nsplit >>= 1;
  const int kchunk = HID / nsplit;

  char* ws = (char*)d_ws;
  double* partial = (double*)ws;
  int*    idx_kt  = (int*)  (ws + (size_t)nsplit * slab);
  float*  w_kt    = (float*)(ws + (size_t)nsplit * slab + (size_t)NK * TOK * 4);
  int*    flag    = (int*)  (ws + (size_t)nsplit * slab + tail);

  // zero the 4.76 GB output (poisoned 0xAA before every timed launch)
  hipMemsetAsync(d_out, 0, (size_t)out_size * sizeof(float), stream);

  dim3 bgrid(TOK / 64, nsplit);   // 64 x 8 = 512 blocks
  dim3 rgrid(TOK / 16, nsplit);   // repair: 256 x 8
  gemm_bf16x3  <<<bgrid, 256, 0, stream>>>(x, wg, partial, kchunk, flag);
  verify_kernel<<<128, 256, 0, stream>>>(x, wg, partial, nsplit, flag);
  repair_splitk<<<rgrid, 256, 0, stream>>>(x, wg, partial, kchunk, flag);
  topk_kernel  <<<TOK * 64 / 256, 256, 0, stream>>>(partial, nsplit, idx_kt, w_kt);
  rank_scatter <<<NE, 1024, 0, stream>>>(idx_kt, w_kt, out, C);
}